// Round 8
// baseline (51.200 us; speedup 1.0000x reference)
//
#include <hip/hip_runtime.h>

#define LENY  1048576
#define NU    (LENY - 1)      // length of u_combined
#define NRBF  11
#define NB    2048            // 8 blocks/CU -> 32 waves/CU (exact-fit co-resident)
#define NT    256             // 4 waves per block
#define NW    (NT / 64)
#define PERT  2               // consecutive elements per thread
#define CHUNK (NT * PERT)     // 512; NB*CHUNK == LENY

typedef float v4f __attribute__((ext_vector_type(4)));

#define L2E 1.44269504088896340736f   // log2(e)

__device__ __forceinline__ float fexp(float x) {
    return __builtin_amdgcn_exp2f(x * L2E);
}
__device__ __forceinline__ float sigmoid10(float x) {
    x = fminf(10.0f, fmaxf(-10.0f, x));
    const float e = __builtin_amdgcn_exp2f(-x * L2E);
    return __builtin_amdgcn_rcpf(1.0f + e);
}

// Relaxed agent-scope atomics: reach the coherence point, emit NO
// buffer_inv/buffer_wbl2 (acq/rel cache maintenance poisoned R2: 62us).
__device__ __forceinline__ void st_relaxed_u64(unsigned long long* p, unsigned long long v) {
    __hip_atomic_store(p, v, __ATOMIC_RELAXED, __HIP_MEMORY_SCOPE_AGENT);
}
__device__ __forceinline__ unsigned long long ld_relaxed_u64(const unsigned long long* p) {
    return __hip_atomic_load(p, __ATOMIC_RELAXED, __HIP_MEMORY_SCOPE_AGENT);
}
__device__ __forceinline__ void st_relaxed_u32(unsigned* p, unsigned v) {
    __hip_atomic_store(p, v, __ATOMIC_RELAXED, __HIP_MEMORY_SCOPE_AGENT);
}
__device__ __forceinline__ unsigned ld_relaxed_u32(const unsigned* p) {
    return __hip_atomic_load(p, __ATOMIC_RELAXED, __HIP_MEMORY_SCOPE_AGENT);
}
__device__ __forceinline__ double bitsd(unsigned long long v) {
    return __builtin_bit_cast(double, v);
}
__device__ __forceinline__ unsigned long long dbits(double v) {
    return __builtin_bit_cast(unsigned long long, v);
}

// Decoupled-lookback fused scan (CUB-style):
//   flag 0 = invalid, 1 = aggregate available, 2 = inclusive prefix available.
//   agg[] and inc[] are SEPARATE arrays -> no overwrite race on upgrade.
__global__ __launch_bounds__(NT, 8) void rbf_fused(
    const float2* __restrict__ yin,
    const float2* __restrict__ xa,
    const float2* __restrict__ xb,
    const float*  __restrict__ rbfw_raw,
    const float*  __restrict__ weights,
    const float*  __restrict__ g1raw,
    const float*  __restrict__ g2raw,
    float2* __restrict__ yout,
    float2* __restrict__ uout,
    unsigned* __restrict__ flags,
    double2* __restrict__ agg,
    double2* __restrict__ inc)
{
    const int b = blockIdx.x, t = threadIdx.x;
    const int lane = t & 63, wid = t >> 6;
    const int base = b * CHUNK + t * PERT;

    // ---- uniform params ----
    const float RBFw    = sigmoid10(rbfw_raw[0]);
    const float wdt     = RBFw * 0.2f;
    const float negInvL = -L2E / (2.0f * wdt * wdt);
    const float g1 = fexp(g1raw[0]);
    const float g2 = fexp(g2raw[0]);
    const float Bf = (float)(1.0 / 60.0);
    const float2 y0 = yin[0];

    float wj[NRBF];
    #pragma unroll
    for (int j = 0; j < NRBF; ++j) wj[j] = weights[j];

    // ---- 16B/lane nontemporal input loads ----
    const v4f yv = __builtin_nontemporal_load((const v4f*)yin + (base >> 1));
    const v4f av = __builtin_nontemporal_load((const v4f*)xa  + (base >> 1));
    const v4f bv = __builtin_nontemporal_load((const v4f*)xb  + (base >> 1));

    // ---- compute u in registers, per-thread double sums ----
    float ux[PERT], uy[PERT];
    double sx = 0.0, sy = 0.0;
    #pragma unroll
    for (int k = 0; k < PERT; ++k) {
        const int gi = base + k;
        const float ti = ((float)gi - 524287.5f) / 524287.5f;
        float dot = 0.0f;
        #pragma unroll
        for (int j = 0; j < NRBF; ++j) {
            const float c = -1.0f + 0.2f * (float)j;
            const float d = ti - c;
            dot += __builtin_amdgcn_exp2f(d * d * negInvL) * wj[j];
        }
        const float wt = sigmoid10(dot);
        const float eyx = yv[2*k], eyy = yv[2*k+1];
        const float eax = av[2*k], eay = av[2*k+1];
        const float ebx = bv[2*k], eby = bv[2*k+1];
        const float u1x = -g1 * (eyx - eax);
        const float u1y = -g1 * (eyy - eay);
        const float u2x = -g2 * (eyx - ebx);
        const float u2y = -g2 * (eyy - eby);
        ux[k] = u1x * (1.0f - wt) + u2x * wt;
        uy[k] = u1y * (1.0f - wt) + u2y * wt;
        sx += (double)(ux[k] * Bf);   // phantom elem LENY-1: exclusive scan means
        sy += (double)(uy[k] * Bf);   // it never reaches any stored prefix
    }

    // ---- block scan: wave shfl_up + wave totals (1 barrier) ----
    double ix = sx, iy = sy;
    #pragma unroll
    for (int d = 1; d < 64; d <<= 1) {
        const double px = __shfl_up(ix, d, 64);
        const double py = __shfl_up(iy, d, 64);
        if (lane >= d) { ix += px; iy += py; }
    }
    __shared__ double2 wtot[NW];
    if (lane == 63) wtot[wid] = make_double2(ix, iy);
    __syncthreads();
    double wbx = 0.0, wby = 0.0, totx = 0.0, toty = 0.0;
    #pragma unroll
    for (int w = 0; w < NW; ++w) {
        const double vx = wtot[w].x, vy = wtot[w].y;
        totx += vx; toty += vy;
        if (w < wid) { wbx += vx; wby += vy; }
    }
    const double myex = wbx + ix - sx;   // exclusive in-block prefix
    const double myey = wby + iy - sy;

    // ---- publish AGGREGATE immediately: payload -> vmcnt(0) -> flag=1 ----
    if (t == 0) {
        st_relaxed_u64((unsigned long long*)&agg[b].x, dbits(totx));
        st_relaxed_u64((unsigned long long*)&agg[b].y, dbits(toty));
        asm volatile("s_waitcnt vmcnt(0)" ::: "memory");
        st_relaxed_u32(&flags[b], 1u);
    }

    // ---- store u (overlaps the lookback) ----
    if (base + PERT <= NU) {
        v4f r = { ux[0], uy[0], ux[1], uy[1] };
        __builtin_nontemporal_store(r, (v4f*)uout + (base >> 1));
    } else {
        for (int k = 0; k < PERT; ++k)
            if (base + k < NU) uout[base + k] = make_float2(ux[k], uy[k]);
    }

    // ---- decoupled lookback, 256-wide windows (all 4 waves) ----
    __shared__ double2 lds_vA[NW];   // per-wave sum of aggregates (whole wave)
    __shared__ double2 lds_vB[NW];   // per-wave sum up to nearest inclusive
    __shared__ int     lds_inc[NW];
    double accx = 0.0, accy = 0.0;
    int j = b - 1;
    while (j >= 0) {
        const int idx = j - t;            // t=0 reads nearest predecessor
        int fl = 0;
        if (idx >= 0) {
            do {
                fl = (int)ld_relaxed_u32(&flags[idx]);
                if (!fl) __builtin_amdgcn_s_sleep(1);
            } while (!fl);
        }
        asm volatile("" ::: "memory");    // don't hoist payload loads above spin
        double ax = 0.0, ay = 0.0;
        if (idx >= 0) {
            ax = bitsd(ld_relaxed_u64((const unsigned long long*)&agg[idx].x));
            ay = bitsd(ld_relaxed_u64((const unsigned long long*)&agg[idx].y));
        }
        const unsigned long long incmask = __ballot(fl == 2);
        const int firstInc = incmask ? (__ffsll((unsigned long long)incmask) - 1) : 64;
        double bxv = 0.0, byv = 0.0;
        if (idx >= 0) {
            if (lane < firstInc)       { bxv = ax; byv = ay; }
            else if (lane == firstInc) {
                bxv = bitsd(ld_relaxed_u64((const unsigned long long*)&inc[idx].x));
                byv = bitsd(ld_relaxed_u64((const unsigned long long*)&inc[idx].y));
            }
        }
        // two wave reduces (full-agg and up-to-inc variants)
        double rax = ax, ray = ay, rbx = bxv, rby = byv;
        #pragma unroll
        for (int d = 32; d > 0; d >>= 1) {
            rax += __shfl_down(rax, d); ray += __shfl_down(ray, d);
            rbx += __shfl_down(rbx, d); rby += __shfl_down(rby, d);
        }
        if (lane == 0) {
            lds_vA[wid]  = make_double2(rax, ray);
            lds_vB[wid]  = make_double2(rbx, rby);
            lds_inc[wid] = (incmask != 0ull);
        }
        __syncthreads();
        // combine the 4 wave windows, nearest first (uniform on all threads)
        double wx = 0.0, wy = 0.0; int found = 0;
        #pragma unroll
        for (int w = 0; w < NW; ++w) {
            if (!found) {
                if (lds_inc[w]) { wx += lds_vB[w].x; wy += lds_vB[w].y; found = 1; }
                else            { wx += lds_vA[w].x; wy += lds_vA[w].y; }
            }
        }
        accx += wx; accy += wy;
        __syncthreads();                  // LDS reuse next window
        if (found) break;
        j -= NT;
    }
    const double offx = accx, offy = accy;

    // ---- publish INCLUSIVE prefix: payload -> vmcnt(0) -> flag=2 ----
    if (t == 0) {
        st_relaxed_u64((unsigned long long*)&inc[b].x, dbits(offx + totx));
        st_relaxed_u64((unsigned long long*)&inc[b].y, dbits(offy + toty));
        asm volatile("s_waitcnt vmcnt(0)" ::: "memory");
        st_relaxed_u32(&flags[b], 2u);
    }

    // ---- exclusive-scan y write (16B nt stores; y[0]=yin[0] falls out) ----
    double runx = offx + myex, runy = offy + myey;
    const double y0x = (double)y0.x, y0y = (double)y0.y;

    const float o0x = (float)(y0x + runx);
    const float o0y = (float)(y0y + runy);
    runx += (double)(ux[0] * Bf);
    runy += (double)(uy[0] * Bf);
    const float o1x = (float)(y0x + runx);
    const float o1y = (float)(y0y + runy);
    v4f r = { o0x, o0y, o1x, o1y };
    __builtin_nontemporal_store(r, (v4f*)yout + (base >> 1));
}

extern "C" void kernel_launch(void* const* d_in, const int* in_sizes, int n_in,
                              void* d_out, int out_size, void* d_ws, size_t ws_size,
                              hipStream_t stream) {
    const float2* yin  = (const float2*)d_in[0];
    const float2* xa   = (const float2*)d_in[1];
    const float2* xb   = (const float2*)d_in[2];
    const float*  rbfw = (const float*)d_in[3];
    const float*  wts  = (const float*)d_in[4];
    const float*  g1   = (const float*)d_in[5];
    const float*  g2   = (const float*)d_in[6];

    float*  out  = (float*)d_out;
    float2* yout = (float2*)out;                 // y: LENY x 2
    float2* uout = (float2*)(out + 2 * LENY);    // u_combined: (LENY-1) x 2

    unsigned* flags = (unsigned*)d_ws;                              //  8 KB
    double2*  agg   = (double2*)((char*)d_ws + 8192);               // 32 KB
    double2*  inc   = (double2*)((char*)d_ws + 8192 + 32768);       // 32 KB

    // flags must be 0 at kernel start on every replay (d_ws not re-poisoned).
    hipMemsetAsync(flags, 0, NB * sizeof(unsigned), stream);

    rbf_fused<<<NB, NT, 0, stream>>>(yin, xa, xb, rbfw, wts, g1, g2,
                                     yout, uout, flags, agg, inc);
}